// Round 3
// baseline (29.222 us; speedup 1.0000x reference)
//
#include <hip/hip_runtime.h>

// MaxPool3d fused: x[8,64,256,256] f32, kernel=stride=(2,2,2), pad 0
// -> out[8,32,128,128] f32.
// Each thread: 8x v4f nontemporal loads (2 rows x 2 depths x 2 W-chunks),
// elementwise max, horizontal pair-max -> v4f nontemporal store (4 outputs).

#define B   8
#define D   64
#define H   256
#define W   256
#define OD  (D / 2)
#define OH  (H / 2)
#define OW  (W / 2)

typedef float v4f __attribute__((ext_vector_type(4)));

__global__ __launch_bounds__(256) void maxpool3d_kernel(
    const float* __restrict__ x, float* __restrict__ out) {
    // total v4f outputs: B*OD*OH*(OW/4) = 1,048,576
    unsigned tid = blockIdx.x * 256u + threadIdx.x;

    unsigned ow4 = tid & 31u;          // OW/4 = 32 v4f per output row
    unsigned t   = tid >> 5;
    unsigned oh  = t & 127u;           // OH = 128
    t >>= 7;
    unsigned od  = t & 31u;            // OD = 32
    unsigned b   = t >> 5;

    // input base: [b][od*2][oh*2][ow4*8]
    const size_t plane = (size_t)H * W;            // 65536
    const size_t ibase = (((size_t)b * D + od * 2u) * H + oh * 2u) * W + ow4 * 8u;

    const v4f* p = (const v4f*)(x + ibase);            // d,   h
    const v4f* q = (const v4f*)(x + ibase + W);        // d,   h+1
    const v4f* r = (const v4f*)(x + ibase + plane);    // d+1, h
    const v4f* s = (const v4f*)(x + ibase + plane + W);// d+1, h+1

    v4f a0 = __builtin_nontemporal_load(p);
    v4f a1 = __builtin_nontemporal_load(p + 1);
    v4f b0 = __builtin_nontemporal_load(q);
    v4f b1 = __builtin_nontemporal_load(q + 1);
    v4f c0 = __builtin_nontemporal_load(r);
    v4f c1 = __builtin_nontemporal_load(r + 1);
    v4f d0 = __builtin_nontemporal_load(s);
    v4f d1 = __builtin_nontemporal_load(s + 1);

    v4f m0, m1;
    m0.x = fmaxf(fmaxf(a0.x, b0.x), fmaxf(c0.x, d0.x));
    m0.y = fmaxf(fmaxf(a0.y, b0.y), fmaxf(c0.y, d0.y));
    m0.z = fmaxf(fmaxf(a0.z, b0.z), fmaxf(c0.z, d0.z));
    m0.w = fmaxf(fmaxf(a0.w, b0.w), fmaxf(c0.w, d0.w));
    m1.x = fmaxf(fmaxf(a1.x, b1.x), fmaxf(c1.x, d1.x));
    m1.y = fmaxf(fmaxf(a1.y, b1.y), fmaxf(c1.y, d1.y));
    m1.z = fmaxf(fmaxf(a1.z, b1.z), fmaxf(c1.z, d1.z));
    m1.w = fmaxf(fmaxf(a1.w, b1.w), fmaxf(c1.w, d1.w));

    v4f o;
    o.x = fmaxf(m0.x, m0.y);
    o.y = fmaxf(m0.z, m0.w);
    o.z = fmaxf(m1.x, m1.y);
    o.w = fmaxf(m1.z, m1.w);

    // output index: [b][od][oh][ow4*4]
    const size_t obase = (((size_t)b * OD + od) * OH + oh) * OW + ow4 * 4u;
    __builtin_nontemporal_store(o, (v4f*)(out + obase));
}

extern "C" void kernel_launch(void* const* d_in, const int* in_sizes, int n_in,
                              void* d_out, int out_size, void* d_ws, size_t ws_size,
                              hipStream_t stream) {
    const float* x = (const float*)d_in[0];
    float* out = (float*)d_out;

    const unsigned total_f4 = B * OD * OH * (OW / 4);  // 1,048,576
    const unsigned blocks = total_f4 / 256u;            // 4096
    maxpool3d_kernel<<<blocks, 256, 0, stream>>>(x, out);
}

// Round 4
// 27.183 us; speedup vs baseline: 1.0750x; 1.0750x over previous
//
#include <hip/hip_runtime.h>

// MaxPool3d fused: x[8,64,256,256] f32, kernel=stride=(2,2,2), pad 0
// -> out[8,32,128,128] f32.
// Each thread: 8x v4f cached loads (2 rows x 2 depths x 2 W-chunks),
// elementwise max, horizontal pair-max -> v4f nontemporal store (4 outputs).
// NT only on store: working set (144 MiB) fits L3; NT loads regressed (R3).

#define B   8
#define D   64
#define H   256
#define W   256
#define OD  (D / 2)
#define OH  (H / 2)
#define OW  (W / 2)

typedef float v4f __attribute__((ext_vector_type(4)));

__global__ __launch_bounds__(256) void maxpool3d_kernel(
    const float* __restrict__ x, float* __restrict__ out) {
    // total v4f outputs: B*OD*OH*(OW/4) = 1,048,576
    unsigned tid = blockIdx.x * 256u + threadIdx.x;

    unsigned ow4 = tid & 31u;          // OW/4 = 32 v4f per output row
    unsigned t   = tid >> 5;
    unsigned oh  = t & 127u;           // OH = 128
    t >>= 7;
    unsigned od  = t & 31u;            // OD = 32
    unsigned b   = t >> 5;

    // input base: [b][od*2][oh*2][ow4*8]
    const size_t plane = (size_t)H * W;            // 65536
    const size_t ibase = (((size_t)b * D + od * 2u) * H + oh * 2u) * W + ow4 * 8u;

    const v4f* p = (const v4f*)(x + ibase);            // d,   h
    const v4f* q = (const v4f*)(x + ibase + W);        // d,   h+1
    const v4f* r = (const v4f*)(x + ibase + plane);    // d+1, h
    const v4f* s = (const v4f*)(x + ibase + plane + W);// d+1, h+1

    v4f a0 = p[0];
    v4f a1 = p[1];
    v4f b0 = q[0];
    v4f b1 = q[1];
    v4f c0 = r[0];
    v4f c1 = r[1];
    v4f d0 = s[0];
    v4f d1 = s[1];

    v4f m0, m1;
    m0.x = fmaxf(fmaxf(a0.x, b0.x), fmaxf(c0.x, d0.x));
    m0.y = fmaxf(fmaxf(a0.y, b0.y), fmaxf(c0.y, d0.y));
    m0.z = fmaxf(fmaxf(a0.z, b0.z), fmaxf(c0.z, d0.z));
    m0.w = fmaxf(fmaxf(a0.w, b0.w), fmaxf(c0.w, d0.w));
    m1.x = fmaxf(fmaxf(a1.x, b1.x), fmaxf(c1.x, d1.x));
    m1.y = fmaxf(fmaxf(a1.y, b1.y), fmaxf(c1.y, d1.y));
    m1.z = fmaxf(fmaxf(a1.z, b1.z), fmaxf(c1.z, d1.z));
    m1.w = fmaxf(fmaxf(a1.w, b1.w), fmaxf(c1.w, d1.w));

    v4f o;
    o.x = fmaxf(m0.x, m0.y);
    o.y = fmaxf(m0.z, m0.w);
    o.z = fmaxf(m1.x, m1.y);
    o.w = fmaxf(m1.z, m1.w);

    // output index: [b][od][oh][ow4*4]
    const size_t obase = (((size_t)b * OD + od) * OH + oh) * OW + ow4 * 4u;
    __builtin_nontemporal_store(o, (v4f*)(out + obase));
}

extern "C" void kernel_launch(void* const* d_in, const int* in_sizes, int n_in,
                              void* d_out, int out_size, void* d_ws, size_t ws_size,
                              hipStream_t stream) {
    const float* x = (const float*)d_in[0];
    float* out = (float*)d_out;

    const unsigned total_f4 = B * OD * OH * (OW / 4);  // 1,048,576
    const unsigned blocks = total_f4 / 256u;            // 4096
    maxpool3d_kernel<<<blocks, 256, 0, stream>>>(x, out);
}